// Round 7
// baseline (243.289 us; speedup 1.0000x reference)
//
#include <hip/hip_runtime.h>
#include <hip/hip_fp16.h>
#include <stdint.h>

// AQT int8 MLP: M=8192, C=1024, H=4096. All I/O float32.
// Exact path: fake_quant values are q/s (integer q), so xq@wq is exact in int32 MFMA.
// 4 dispatches: stats -> quant(x,W1t,W2t) -> GEMM1(h fp16-frag + block hmax)
//            -> GEMM2 (fused: hmax reduce + packed magic-quant of h + GEMM + bias).
//
// int8 operands in MFMA-FRAGMENT ORDER: frag = 1KB = 32 rows x 32 k;
//   byte lane*16+j <-> (row=lane&31, k=(lane>>5)*16+j); frag id = rowblk*(K/32)+kblk.
// h stored fp16 in fragment order: frag = 2KB; halfword ((k>>4)*32+r)*16+(k&15).
// Magic quant: fp32 fma(x,s,1.5*2^23) -> low byte = int8 q; fp16 hfma2(h,s,1536).
//
// Round-6 postmortem: EVERY prior variant had some operand at issue->use = 1
// K-step -> each step pays an unhidden load latency (~600-1500cy vs ~300cy
// compute) -> the invariant 23% MfmaUtil / ~56us. Fix: DEPTH-3 pipelines.
// Both GEMMs: 8 waves (4m x 2n), 128x128 tile, wave=32m x 64n, acc[2];
//   B: 4-slot LDS ring (32KB), async16 issued 3 steps ahead;
//   A: register ring issued 2-3 steps ahead (gemm2: quant = the copy that
//   frees the parity set; gemm1: 4-set ring).
// In-order vmcnt: B(kb+1) forced landed by the wave's own wait on younger
// A-regs (gemm2) or explicit counted vmcnt (gemm1) BEFORE s_barrier;
// counted waits never drain in steady state. 16 waves/CU.

#define EPSQ 1e-6f
typedef int v4i __attribute__((ext_vector_type(4)));
typedef int v16i __attribute__((ext_vector_type(16)));

__device__ __forceinline__ void async16(const int8_t* g, int8_t* l) {
  __builtin_amdgcn_global_load_lds(
      (const __attribute__((address_space(1))) void*)g,
      (__attribute__((address_space(3))) void*)l, 16, 0, 0);
}
__device__ __forceinline__ unsigned short f2h(float f) {
  __half h = __float2half(f);
  return *(unsigned short*)&h;
}
__device__ __forceinline__ float4 max4(float4 m, float4 v) {
  m.x = fmaxf(m.x, fabsf(v.x)); m.y = fmaxf(m.y, fabsf(v.y));
  m.z = fmaxf(m.z, fabsf(v.z)); m.w = fmaxf(m.w, fabsf(v.w));
  return m;
}
// fp32 magic quant: |x*s| <= 127 guaranteed by construction (s = 127/absmax).
__device__ __forceinline__ unsigned qmb(float x, float s) {
  return __float_as_uint(fmaf(x, s, 12582912.0f)) & 0xffu;   // 1.5*2^23
}
__device__ __forceinline__ unsigned q4f(float4 f, float s) {
  return qmb(f.x, s) | (qmb(f.y, s) << 8) | (qmb(f.z, s) << 16) |
         (__float_as_uint(fmaf(f.w, s, 12582912.0f)) << 24);
}
// fp16 packed magic quant: two halfs -> ... -> select low bytes of 4 halfs.
__device__ __forceinline__ unsigned q4h(unsigned ua, unsigned ub,
                                        __half2 s2, __half2 m2) {
  __half2 ha = __hfma2(*(__half2*)&ua, s2, m2);
  __half2 hb = __hfma2(*(__half2*)&ub, s2, m2);
  unsigned va = *(unsigned*)&ha, vb = *(unsigned*)&hb;
#if __has_builtin(__builtin_amdgcn_perm)
  return __builtin_amdgcn_perm(vb, va, 0x06040200u);
#else
  return (va & 0xffu) | ((va >> 8) & 0xff00u) |
         ((vb & 0xffu) << 16) | (((vb >> 8) & 0xff00u) << 16);
#endif
}

// ===== dispatch 1: stats. W1: 16 rowsplits x 4 colgroups; W2: 64 rowsplits;
// x masked absmax: 1024 blk. =====
__global__ __launch_bounds__(256) void k_stats(
    const float* __restrict__ x, const float* __restrict__ mask,
    const float* __restrict__ W1, const float* __restrict__ W2,
    float* __restrict__ pmaxX, float* __restrict__ pcm1, float* __restrict__ pcm2) {
  const int bx = blockIdx.x, tid = threadIdx.x;
  if (bx < 64) {                       // W1 [1024,4096]
    const int sp = bx & 15, cg = bx >> 4;
    const int col = cg * 1024 + tid * 4;
    float4 m = {0.f, 0.f, 0.f, 0.f};
#pragma unroll 8
    for (int r = 0; r < 64; ++r)
      m = max4(m, *(const float4*)(W1 + (size_t)(sp * 64 + r) * 4096 + col));
    *(float4*)(pcm1 + sp * 4096 + col) = m;
  } else if (bx < 128) {               // W2 [4096,1024]
    const int sp = bx - 64;
    const int col = tid * 4;
    float4 m = {0.f, 0.f, 0.f, 0.f};
#pragma unroll 8
    for (int r = 0; r < 64; ++r)
      m = max4(m, *(const float4*)(W2 + (size_t)(sp * 64 + r) * 1024 + col));
    *(float4*)(pcm2 + sp * 1024 + col) = m;
  } else {                             // masked absmax of x -> per-block partial
    __shared__ float red[4];
    const int b = bx - 128;            // 1024 blocks
    float lmax = 0.f;
    for (int c = b * 256 + tid; c < 1048576; c += 262144) {
      size_t idx = (size_t)c * 8;
      float mk = fabsf(mask[idx >> 10]);
      float4 m4 = {0.f, 0.f, 0.f, 0.f};
      m4 = max4(m4, *(const float4*)(x + idx));
      m4 = max4(m4, *(const float4*)(x + idx + 4));
      lmax = fmaxf(lmax, fmaxf(fmaxf(m4.x, m4.y), fmaxf(m4.z, m4.w)) * mk);
    }
    for (int s = 32; s; s >>= 1) lmax = fmaxf(lmax, __shfl_down(lmax, s));
    if ((tid & 63) == 0) red[tid >> 6] = lmax;
    __syncthreads();
    if (tid == 0)
      pmaxX[b] = fmaxf(fmaxf(red[0], red[1]), fmaxf(red[2], red[3]));
  }
}

// ===== dispatch 2: quantize x (2048 blk, frag order), W1->qW1t (256), W2->qW2t (256)
__global__ __launch_bounds__(256) void k_quant(
    const float* __restrict__ x, const float* __restrict__ W1, const float* __restrict__ W2,
    const float* __restrict__ pmaxX, const float* __restrict__ pcm1, const float* __restrict__ pcm2,
    int8_t* __restrict__ qx, int8_t* __restrict__ qw1, int8_t* __restrict__ qw2,
    float* __restrict__ cm1, float* __restrict__ cm2, float* __restrict__ scG) {
  const int bx = blockIdx.x, tid = threadIdx.x;
  if (bx < 2048) {                     // x [8192,1024] -> qx frag order
    __shared__ float red[4];
    float v = fmaxf(fmaxf(pmaxX[tid], pmaxX[tid + 256]),
                    fmaxf(pmaxX[tid + 512], pmaxX[tid + 768]));
    for (int s = 32; s; s >>= 1) v = fmaxf(v, __shfl_down(v, s));
    if ((tid & 63) == 0) red[tid >> 6] = v;
    __syncthreads();
    const float xmax = fmaxf(fmaxf(red[0], red[1]), fmaxf(red[2], red[3]));
    if (bx == 0 && tid == 0) scG[0] = xmax;
    const float s = 127.0f / fmaxf(xmax, EPSQ);
    const int wave = tid >> 6, lane = tid & 63;
    const int f = bx * 4 + wave;                   // frag id; Kf = 1024/32 = 32
    const int r = (f >> 5) * 32 + (lane & 31);
    const int k = (f & 31) * 32 + (lane >> 5) * 16;
    const float4* src = (const float4*)(x + (size_t)r * 1024 + k);
    uint4 o;
    o.x = q4f(src[0], s); o.y = q4f(src[1], s);
    o.z = q4f(src[2], s); o.w = q4f(src[3], s);
    *(uint4*)(qx + (size_t)f * 1024 + lane * 16) = o;
  } else if (bx < 2304) {              // W1 [1024,4096] -> qw1t frags [4096 n, 1024 k]
    int id = (bx - 2048) * 256 + tid;  // 65536 tasks: 4 cols x 16 k each
    int n4 = id & 1023, kc = id >> 10; // col=n4*4, kc in 0..63 (16-k chunks)
    const int col = n4 * 4;
    float4 cm = {0.f, 0.f, 0.f, 0.f};
#pragma unroll
    for (int sp = 0; sp < 16; ++sp) {
      float4 p = *(const float4*)(pcm1 + sp * 4096 + col);
      cm.x = fmaxf(cm.x, p.x); cm.y = fmaxf(cm.y, p.y);
      cm.z = fmaxf(cm.z, p.z); cm.w = fmaxf(cm.w, p.w);
    }
    if (kc == 0) *(float4*)(cm1 + col) = cm;
    const float s0 = 127.0f / fmaxf(cm.x, EPSQ), s1 = 127.0f / fmaxf(cm.y, EPSQ);
    const float s2 = 127.0f / fmaxf(cm.z, EPSQ), s3 = 127.0f / fmaxf(cm.w, EPSQ);
    union { int8_t p[16]; uint4 v; } u0, u1, u2, u3;
#pragma unroll
    for (int j = 0; j < 16; ++j) {
      float4 f = *(const float4*)(W1 + (size_t)(kc * 16 + j) * 4096 + col);
      u0.p[j] = (int8_t)qmb(f.x, s0); u1.p[j] = (int8_t)qmb(f.y, s1);
      u2.p[j] = (int8_t)qmb(f.z, s2); u3.p[j] = (int8_t)qmb(f.w, s3);
    }
    // frag-order dest: frag=((col>>5)*(1024/32) + (kc>>1)), half=(kc&1)
    int8_t* base = qw1 + ((size_t)(col >> 5) * 32 + (kc >> 1)) * 1024 +
                   (kc & 1) * 512 + (col & 31) * 16;
    *(uint4*)(base) = u0.v;      *(uint4*)(base + 16) = u1.v;
    *(uint4*)(base + 32) = u2.v; *(uint4*)(base + 48) = u3.v;
  } else {                             // W2 [4096,1024] -> qw2t frags [1024 n, 4096 k]
    int id = (bx - 2304) * 256 + tid;  // 65536 tasks
    int n4 = id & 255, kc = id >> 8;   // col=n4*4, kc in 0..255
    const int col = n4 * 4;
    float4 cm = {0.f, 0.f, 0.f, 0.f};
#pragma unroll
    for (int sp = 0; sp < 64; ++sp) {
      float4 p = *(const float4*)(pcm2 + sp * 1024 + col);
      cm.x = fmaxf(cm.x, p.x); cm.y = fmaxf(cm.y, p.y);
      cm.z = fmaxf(cm.z, p.z); cm.w = fmaxf(cm.w, p.w);
    }
    if (kc == 0) *(float4*)(cm2 + col) = cm;
    const float s0 = 127.0f / fmaxf(cm.x, EPSQ), s1 = 127.0f / fmaxf(cm.y, EPSQ);
    const float s2 = 127.0f / fmaxf(cm.z, EPSQ), s3 = 127.0f / fmaxf(cm.w, EPSQ);
    union { int8_t p[16]; uint4 v; } u0, u1, u2, u3;
#pragma unroll
    for (int j = 0; j < 16; ++j) {
      float4 f = *(const float4*)(W2 + (size_t)(kc * 16 + j) * 1024 + col);
      u0.p[j] = (int8_t)qmb(f.x, s0); u1.p[j] = (int8_t)qmb(f.y, s1);
      u2.p[j] = (int8_t)qmb(f.z, s2); u3.p[j] = (int8_t)qmb(f.w, s3);
    }
    int8_t* base = qw2 + ((size_t)(col >> 5) * 128 + (kc >> 1)) * 1024 +
                   (kc & 1) * 512 + (col & 31) * 16;
    *(uint4*)(base) = u0.v;      *(uint4*)(base + 16) = u1.v;
    *(uint4*)(base + 32) = u2.v; *(uint4*)(base + 48) = u3.v;
  }
}

// ====== GEMM1: qx [M=8192, K=1024] x qw1t [N=4096, K].
// 8 waves (4m x 2n), 128x128 tile, wave=32m x 64n, acc[2]. Grid 2048.
// A: qx int8 direct global->reg, 4-set ring, issued 3 steps ahead (2 v4i/step).
// B: 4-slot LDS ring (32KB), 1 async16/wave/step, issued 3 steps ahead.
// End-of-step s_waitcnt vmcnt(8) (counted; forces B(kb+1), keeps rest flying).
// Output: h fp16 FRAG ORDER direct stores + per-block masked hmax. ======
__global__ __launch_bounds__(512, 4) void gemm1(
    const int8_t* __restrict__ A, const int8_t* __restrict__ Bt,
    const float* __restrict__ sxp, const float* __restrict__ cmax,
    const float* __restrict__ bias, const float* __restrict__ mask,
    unsigned short* __restrict__ hfrag, float* __restrict__ pmaxH) {
  constexpr int NST = 16;              // K=1024 / 64
  __shared__ __align__(16) int8_t smem[4 * 8192];    // B ring, 4 slots
  const int tid = threadIdx.x;
  const int wave = tid >> 6, lane = tid & 63;

  // XCD swizzle: xcd owns 8 m-tiles x all 32 n-tiles (A 1MB + B 4MB ~ L2).
  // sl sweeps m inner, n outer -> B-frag reuse across m within XCD.
  const int bid = blockIdx.x;          // grid 2048 = 64 m x 32 n
  const int xcd = bid & 7, sl = bid >> 3;            // sl in 0..255
  const int m0 = (xcd * 8 + (sl & 7)) * 128;
  const int n0 = (sl >> 3) * 128;
  const int wr = wave & 3, wc = wave >> 2;           // 4m x 2n wave grid

  v16i acc[2] = {};

  // A: wave's rowblock rb=(m0>>5)+wr (shared by 2 n-waves; L1 dedups).
  // frag byte = (rb*32 + kb*2 + kc)*1024 + lane*16; step stride 2048.
  const int8_t* gA = A + ((size_t)((m0 >> 5) + wr) * 32) * 1024 + lane * 16;
  // B staging: wave stages frag (kcS=wave>>2, nfS=wave&3) == frag idx `wave`.
  const int8_t* gB = Bt + ((size_t)((n0 >> 5) + (wave & 3)) * 32 + (wave >> 2)) * 1024
                     + lane * 16;
  const int dBo = wave * 1024 + lane * 16;
  const int rdo = lane * 16;           // B read: slot + (kc*4 + wc*2+nt)*1024 + rdo

  // A 4-set ring (2 v4i each), depth 3: set t&3 holds A(t).
  v4i a0k0 = {}, a0k1 = {}, a1k0 = {}, a1k1 = {};
  v4i a2k0 = {}, a2k1 = {}, a3k0 = {}, a3k1 = {};

  // prologue: B(0),B(1),B(2) then A(0),A(1),A(2)  (order matters for vmcnt)
  async16(gB,        smem + dBo);
  async16(gB + 2048, smem + 8192 + dBo);
  async16(gB + 4096, smem + 16384 + dBo);
  __builtin_amdgcn_sched_barrier(0);
  a0k0 = *(const v4i*)(gA);        a0k1 = *(const v4i*)(gA + 1024);
  a1k0 = *(const v4i*)(gA + 2048); a1k1 = *(const v4i*)(gA + 3072);
  a2k0 = *(const v4i*)(gA + 4096); a2k1 = *(const v4i*)(gA + 5120);
  asm volatile("s_waitcnt vmcnt(8)" ::: "memory");   // B(0) landed; rest flying
  __builtin_amdgcn_s_barrier();
  __builtin_amdgcn_sched_barrier(0);

#pragma unroll 4
  for (int kb = 0; kb < NST; ++kb) {
    const int slot = (kb & 3) * 8192;
    if (kb + 3 < NST) {                              // B(kb+3) -> slot (kb+3)&3
      async16(gB + (size_t)(kb + 3) * 2048, smem + ((kb + 3) & 3) * 8192 + dBo);
      __builtin_amdgcn_sched_barrier(0);             // B before A (vmcnt order)
      const int8_t* ga = gA + (size_t)(kb + 3) * 2048;
      const int d = (kb + 3) & 3;                    // static under unroll 4
      if (d == 0)      { a0k0 = *(const v4i*)ga; a0k1 = *(const v4i*)(ga + 1024); }
      else if (d == 1) { a1k0 = *(const v4i*)ga; a1k1 = *(const v4i*)(ga + 1024); }
      else if (d == 2) { a2k0 = *(const v4i*)ga; a2k1 = *(const v4i*)(ga + 1024); }
      else             { a3k0 = *(const v4i*)ga; a3k1 = *(const v4i*)(ga + 1024); }
      __builtin_amdgcn_sched_barrier(0);
    }
    {
      const int s = kb & 3;                          // static under unroll 4
      v4i af0, af1;
      if (s == 0)      { af0 = a0k0; af1 = a0k1; }
      else if (s == 1) { af0 = a1k0; af1 = a1k1; }
      else if (s == 2) { af0 = a2k0; af1 = a2k1; }
      else             { af0 = a3k0; af1 = a3k1; }
      v4i b00 = *(const v4i*)(smem + slot + (0 * 4 + wc * 2 + 0) * 1024 + rdo);
      v4i b01 = *(const v4i*)(smem + slot + (0 * 4 + wc * 2 + 1) * 1024 + rdo);
      v4i b10 = *(const v4i*)(smem + slot + (1 * 4 + wc * 2 + 0) * 1024 + rdo);
      v4i b11 = *(const v4i*)(smem + slot + (1 * 4 + wc * 2 + 1) * 1024 + rdo);
      __builtin_amdgcn_s_setprio(1);
      acc[0] = __builtin_amdgcn_mfma_i32_32x32x32_i8(af0, b00, acc[0], 0, 0, 0);
      acc[1] = __builtin_amdgcn_mfma_i32_32x32x32_i8(af0, b01, acc[1], 0, 0, 0);
      acc[0] = __builtin_amdgcn_mfma_i32_32x32x32_i8(af1, b10, acc[0], 0, 0, 0);
      acc[1] = __builtin_amdgcn_mfma_i32_32x32x32_i8(af1, b11, acc[1], 0, 0, 0);
      __builtin_amdgcn_s_setprio(0);
    }
    // counted wait: newest 8 = {A(kb+1)x2, B(kb+2), A(kb+2)x2, B(kb+3), A(kb+3)x2}
    // -> forces B(kb+1) landed (this wave's own DMA) before cross-wave barrier.
    if (kb + 3 < NST) asm volatile("s_waitcnt vmcnt(8)" ::: "memory");
    else              asm volatile("s_waitcnt vmcnt(0)" ::: "memory");
    __builtin_amdgcn_s_barrier();
    __builtin_amdgcn_sched_barrier(0);
  }

  // epilogue: C/D layout col=lane&31, row=(reg&3)+8*(reg>>2)+4*(lane>>5).
  const float asc = fmaxf(sxp[0], EPSQ) * (1.0f / 127.0f);
  const int cl = lane & 31;
  const int rbase = 4 * (lane >> 5);
  float bsc[2], bv[2];
#pragma unroll
  for (int nt = 0; nt < 2; ++nt) {
    const int col = n0 + wc * 64 + nt * 32 + cl;
    bsc[nt] = fmaxf(cmax[col], EPSQ) * (1.0f / 127.0f) * asc;
    bv[nt] = bias[col];
  }
  const int hwoff = (cl >> 4) * 512 + (cl & 15);     // within-frag halfword for k=cl
  const int rowbase = m0 + wr * 32;
  const size_t rowblk = (size_t)(rowbase >> 5);
  float lmax = 0.f;
#pragma unroll
  for (int g = 0; g < 4; ++g)
#pragma unroll
    for (int r2 = 0; r2 < 4; ++r2) {
      const int rloc = g * 8 + r2 + rbase;
      const float mk = fabsf(mask[rowbase + rloc]);
#pragma unroll
      for (int nt = 0; nt < 2; ++nt) {
        const size_t kblk = (size_t)((n0 + wc * 64 + nt * 32) >> 5);
        float v = (float)acc[nt][g * 4 + r2] * bsc[nt] + bv[nt];
        v = fmaxf(v, 0.f);
        hfrag[(rowblk * 128 + kblk) * 1024 + hwoff + rloc * 16] = f2h(v);
        lmax = fmaxf(lmax, v * mk);
      }
    }
  for (int s = 32; s; s >>= 1) lmax = fmaxf(lmax, __shfl_down(lmax, s));
  __syncthreads();                     // loop LDS traffic fully done; reuse smem
  float* redf = (float*)smem;
  if (lane == 0) redf[wave] = lmax;
  __syncthreads();
  if (tid == 0) {
    float r = redf[0];
#pragma unroll
    for (int j = 1; j < 8; ++j) r = fmaxf(r, redf[j]);
    pmaxH[bid] = r;
  }
}

// ====== GEMM2 (fused): hfrag fp16 [M=8192, K=4096] x qw2t [N=1024, K].
// 8 waves (4m x 2n), 128x128 tile, wave=32m x 64n, acc[2]. Grid 512.
// A: hfrag fp16 global->reg, parity-2 sets issued 2 steps ahead; quant at body
//   top is the copy that frees the set (and its wait transitively lands B(kb+1)).
// B: 4-slot LDS ring (32KB), 1 async16/wave/step, issued 3 steps ahead.
// Out f32 = deq + bias. ======
__global__ __launch_bounds__(512, 4) void gemm2(
    const unsigned short* __restrict__ hfrag, const int8_t* __restrict__ Bt,
    const float* __restrict__ pmaxH, const float* __restrict__ cmax,
    const float* __restrict__ bias, float* __restrict__ out) {
  constexpr int NST = 64;              // K=4096 / 64
  __shared__ __align__(16) int8_t smem[4 * 8192];    // B ring, 4 slots
  const int tid = threadIdx.x;
  const int wave = tid >> 6, lane = tid & 63;

  // hmax = max over 2048 pmaxH partials (red overlaps smem; barrier-fenced)
  float* red = (float*)smem;
  float v = 0.f;
#pragma unroll
  for (int j = 0; j < 4; ++j) v = fmaxf(v, pmaxH[tid + 512 * j]);
  for (int s = 32; s; s >>= 1) v = fmaxf(v, __shfl_down(v, s));
  if (lane == 0) red[wave] = v;
  __syncthreads();
  float hmax = red[0];
#pragma unroll
  for (int j = 1; j < 8; ++j) hmax = fmaxf(hmax, red[j]);
  __syncthreads();                     // red consumed before staging overwrites
  const float asc = fmaxf(hmax, EPSQ) * (1.0f / 127.0f);
  const __half sh = __float2half_rn(127.0f / fmaxf(hmax, EPSQ));
  const __half2 s2 = __halves2half2(sh, sh);
  const __half mh = __float2half_rn(1536.0f);
  const __half2 m2 = __halves2half2(mh, mh);

  // XCD swizzle: xcd owns 8 contiguous m-tiles x all 8 n-tiles.
  const int bid = blockIdx.x;
  const int xcd = bid & 7, slot2 = bid >> 3;
  const int m0 = ((xcd << 3) + (slot2 >> 3)) * 128;
  const int n0 = (slot2 & 7) * 128;
  const int wr = wave & 3, wc = wave >> 2;

  v16i acc[2] = {};

  // A: rowblock rb=(m0>>5)+wr (shared by 2 n-waves; L1 dedups).
  // fp16 frag = 2 uint4/lane: uint4 idx = (rb*128 + kb*2 + kc)*128 + lane*2.
  const uint4* hA = (const uint4*)hfrag;
  const size_t aBase = ((size_t)((m0 >> 5) + wr) * 128) * 128 + (size_t)lane * 2;
  // B staging: wave stages frag (kcS=wave>>2, nfS=wave&3) == frag idx `wave`.
  const int8_t* gB = Bt + ((size_t)((n0 >> 5) + (wave & 3)) * 128 + (wave >> 2)) * 1024
                     + lane * 16;
  const int dBo = wave * 1024 + lane * 16;
  const int rdo = lane * 16;

  // A parity sets (4 uint4 each): P = even kb, Q = odd kb. Depth 2.
  uint4 hP0 = {}, hP1 = {}, hP2 = {}, hP3 = {};
  uint4 hQ0 = {}, hQ1 = {}, hQ2 = {}, hQ3 = {};

  // prologue: B(0),B(1),B(2) then A(0)->P, A(1)->Q.
  async16(gB,        smem + dBo);
  async16(gB + 2048, smem + 8192 + dBo);
  async16(gB + 4096, smem + 16384 + dBo);
  __builtin_amdgcn_sched_barrier(0);
  hP0 = hA[aBase];       hP1 = hA[aBase + 1];
  hP2 = hA[aBase + 128]; hP3 = hA[aBase + 129];
  hQ0 = hA[aBase + 256]; hQ1 = hA[aBase + 257];
  hQ2 = hA[aBase + 384]; hQ3 = hA[aBase + 385];
  asm volatile("s_waitcnt vmcnt(10)" ::: "memory");  // B(0) landed; rest flying
  __builtin_amdgcn_s_barrier();
  __builtin_amdgcn_sched_barrier(0);

#pragma unroll 4
  for (int kb = 0; kb < NST; ++kb) {
    const int slot = (kb & 3) * 8192;
    // (1) quant A(kb) -> operands. Compiler waits the set's loads here, which
    //     (in-order) also retires this wave's B(kb+1) DMA -> barrier-safe.
    v4i af0, af1;
    {
      const uint4 h0 = (kb & 1) ? hQ0 : hP0;
      const uint4 h1 = (kb & 1) ? hQ1 : hP1;
      const uint4 h2 = (kb & 1) ? hQ2 : hP2;
      const uint4 h3 = (kb & 1) ? hQ3 : hP3;
      uint4 oa, ob;
      oa.x = q4h(h0.x, h0.y, s2, m2); oa.y = q4h(h0.z, h0.w, s2, m2);
      oa.z = q4h(h1.x, h1.y, s2, m2); oa.w = q4h(h1.z, h1.w, s2, m2);
      ob.x = q4h(h2.x, h2.y, s2, m2); ob.y = q4h(h2.z, h2.w, s2, m2);
      ob.z = q4h(h3.x, h3.y, s2, m2); ob.w = q4h(h3.z, h3.w, s2, m2);
      af0 = *(const v4i*)&oa;          // kc0 operand
      af1 = *(const v4i*)&ob;          // kc1 operand
    }
    __builtin_amdgcn_sched_barrier(0);
    // (2) issue B(kb+3), then (3) A(kb+2) into the set quant just freed.
    if (kb + 3 < NST)
      async16(gB + (size_t)(kb + 3) * 2048, smem + ((kb + 3) & 3) * 8192 + dBo);
    __builtin_amdgcn_sched_barrier(0);
    if (kb + 2 < NST) {
      const size_t ai = aBase + (size_t)(kb + 2) * 256;
      if (kb & 1) { hQ0 = hA[ai]; hQ1 = hA[ai + 1]; hQ2 = hA[ai + 128]; hQ3 = hA[ai + 129]; }
      else        { hP0 = hA[ai]; hP1 = hA[ai + 1]; hP2 = hA[ai + 128]; hP3 = hA[ai + 129]; }
    }
    __builtin_amdgcn_sched_barrier(0);
    // (4) B reads + (5) MFMA
    {
      v4i b00 = *(const v4i*)(smem + slot + (0 * 4 + wc * 2 + 0) * 1024 + rdo);
      v4i b01 = *(const v4i*)(smem + slot + (0 * 4 + wc * 2 + 1) * 1024 + rdo);
      v4i b10 = *(const v4i*)(smem + slot + (1 * 4 + wc * 2 + 0) * 1024 + rdo);
      v4i b11 = *(const v4i*)(smem + slot + (1 * 4 + wc * 2 + 1) * 1024 + rdo);
      __builtin_amdgcn_s_setprio(1);
      acc[0] = __builtin_amdgcn_mfma_i32_32x32x32_i8(af0, b00, acc[0], 0, 0, 0);
      acc[1] = __builtin_amdgcn_mfma_i32_32x32x32_i8(af0, b01, acc[1], 0, 0, 0);
      acc[0] = __builtin_amdgcn_mfma_i32_32x32x32_i8(af1, b10, acc[0], 0, 0, 0);
      acc[1] = __builtin_amdgcn_mfma_i32_32x32x32_i8(af1, b11, acc[1], 0, 0, 0);
      __builtin_amdgcn_s_setprio(0);
    }
    // (6) counted guard (no-op in steady state; B(kb+1) already forced by (1))
    if (kb + 3 < NST) asm volatile("s_waitcnt vmcnt(10)" ::: "memory");
    else              asm volatile("s_waitcnt vmcnt(0)" ::: "memory");
    __builtin_amdgcn_s_barrier();
    __builtin_amdgcn_sched_barrier(0);
  }

  // epilogue: out f32 row-major [8192,1024]; wave owns 32 rows x 64 cols
  const int cl = lane & 31;
  const int rbase = 4 * (lane >> 5);
  float bsc[2], bv[2];
  int colv[2];
#pragma unroll
  for (int nt = 0; nt < 2; ++nt) {
    colv[nt] = n0 + wc * 64 + nt * 32 + cl;
    bsc[nt] = fmaxf(cmax[colv[nt]], EPSQ) * (1.0f / 127.0f) * asc;
    bv[nt] = bias[colv[nt]];
  }
  const int rowbase = m0 + wr * 32;
#pragma unroll
  for (int g = 0; g < 4; ++g)
#pragma unroll
    for (int r2 = 0; r2 < 4; ++r2) {
      const int row = rowbase + g * 8 + r2 + rbase;
#pragma unroll
      for (int nt = 0; nt < 2; ++nt)
        out[(size_t)row * 1024 + colv[nt]] =
            (float)acc[nt][g * 4 + r2] * bsc[nt] + bv[nt];
    }
}

extern "C" void kernel_launch(void* const* d_in, const int* in_sizes, int n_in,
                              void* d_out, int out_size, void* d_ws, size_t ws_size,
                              hipStream_t stream) {
  const float* x  = (const float*)d_in[0];   // [8192,1024]
  const float* mk = (const float*)d_in[1];   // [8192]
  const float* W1 = (const float*)d_in[2];   // [1024,4096]
  const float* b1 = (const float*)d_in[3];   // [4096]
  const float* W2 = (const float*)d_in[4];   // [4096,1024]
  const float* b2 = (const float*)d_in[5];   // [1024]
  float* out = (float*)d_out;                // [8192,1024]

  float* scG   = (float*)d_ws;               // [8]
  float* pmaxX = scG + 8;                    // [1024]
  float* pmaxH = pmaxX + 1024;               // [2048]
  float* pcm1  = pmaxH + 2048;               // [16*4096]
  float* pcm2  = pcm1 + 65536;               // [64*1024]
  float* cm1   = pcm2 + 65536;               // [4096]
  float* cm2   = cm1 + 4096;                 // [1024]
  int8_t* qx  = (int8_t*)(cm2 + 1024);           // 8 MiB  frag order
  int8_t* qw1 = qx  + (size_t)8192 * 1024;       // 4 MiB  frag order [4096 n][1024 k]
  int8_t* qw2 = qw1 + (size_t)4096 * 1024;       // 4 MiB  frag order [1024 n][4096 k]
  unsigned short* h = (unsigned short*)(qw2 + (size_t)1024 * 4096);  // 64 MiB fp16 frag order

  k_stats<<<1152, 256, 0, stream>>>(x, mk, W1, W2, pmaxX, pcm1, pcm2);
  k_quant<<<2560, 256, 0, stream>>>(x, W1, W2, pmaxX, pcm1, pcm2,
                                    qx, qw1, qw2, cm1, cm2, scG);
  gemm1<<<2048, 512, 0, stream>>>(qx, qw1, scG, cm1, b1, mk, h, pmaxH);
  gemm2<<<512, 512, 0, stream>>>(h, qw2, pmaxH, cm2, b2, out);
}